// Round 3
// baseline (609.273 us; speedup 1.0000x reference)
//
#include <hip/hip_runtime.h>
#include <cstdint>

// ---- types ----
typedef short bf16x8 __attribute__((ext_vector_type(8)));        // 8 bf16 in 4 VGPRs
typedef unsigned short u16x8 __attribute__((ext_vector_type(8)));
typedef float f32x4 __attribute__((ext_vector_type(4)));
typedef __attribute__((address_space(3))) uint32_t lds_u32;
typedef const __attribute__((address_space(1))) uint32_t gbl_u32;

// fp32 -> bf16 bits, round-to-nearest-even
__device__ __forceinline__ unsigned short f2bf(float f) {
  union { float f; uint32_t u; } c; c.f = f;
  uint32_t u = c.u;
  return (unsigned short)((u + 0x7fffu + ((u >> 16) & 1u)) >> 16);
}

// ---- x fp32 -> bf16, 8 elems/thread ----
__global__ void cvt_x_kernel(const float* __restrict__ x,
                             unsigned short* __restrict__ y, long n) {
  long t = (long)blockIdx.x * blockDim.x + threadIdx.x;
  long base = t * 8;
  if (base >= n) return;
  const float4* p = (const float4*)(x + base);
  float4 f0 = p[0], f1 = p[1];
  u16x8 v;
  v[0] = f2bf(f0.x); v[1] = f2bf(f0.y); v[2] = f2bf(f0.z); v[3] = f2bf(f0.w);
  v[4] = f2bf(f1.x); v[5] = f2bf(f1.y); v[6] = f2bf(f1.z); v[7] = f2bf(f1.w);
  *(u16x8*)(y + base) = v;
}

// ---- W dequant: bf16(lut[idx] * scale), 8 elems/thread ----
__global__ void dequant_kernel(const int* __restrict__ idx,
                               const float* __restrict__ lut,
                               const float* __restrict__ scale,
                               unsigned short* __restrict__ w, long n) {
  __shared__ unsigned short slut[16];
  if (threadIdx.x < 15) slut[threadIdx.x] = f2bf(lut[threadIdx.x] * scale[0]);
  __syncthreads();
  long t = (long)blockIdx.x * blockDim.x + threadIdx.x;
  long base = t * 8;
  if (base >= n) return;
  const int4* p = (const int4*)(idx + base);
  int4 i0 = p[0], i1 = p[1];
  u16x8 v;
  v[0] = slut[i0.x]; v[1] = slut[i0.y]; v[2] = slut[i0.z]; v[3] = slut[i0.w];
  v[4] = slut[i1.x]; v[5] = slut[i1.y]; v[6] = slut[i1.z]; v[7] = slut[i1.w];
  *(u16x8*)(w + base) = v;
}

// ============================================================================
// bf16 NT-GEMM, 256x256 tile, BK=64, 8 waves (2Mx4N), 8-phase schedule with
// READ-AHEAD: each phase issues the NEXT phase's ds_reads before its barrier,
// so LDS latency hides under the current MFMA cluster. The compiler derives
// counted lgkmcnt waits from C++ dataflow (guide G7) — no asm lgkm needed.
// vmcnt(6) twice per K-tile (m201 discipline), never 0 in the main loop.
//
// LDS per buffer (32K elems): r0=A ks0 [256][32], r1=A ks1, r2=B ks0, r3=B ks1.
// T2 swizzle (R2-verified, 0 conflicts): stored_chunk = chunk ^ ((row>>1)&3),
// applied on the global SOURCE of global_load_lds + the ds_read address.
//
// Stage ledger (group g = one STAGE = 2 loads), tile t, D = t&1:
//   g(4t+3): ph1(t) B1(t+1)->D^1 r3     g(4t+4): ph2(t) A1(t+1)->D^1 r1
//   g(4t+5): ph3(t) A0(t+2)->D  r0     g(4t+6): ph4(t) B0(t+2)->D  r2
// vmcnt(6) @ph2(t): retires B1(t),A1(t)  (3 newer groups in flight)
// vmcnt(6) @ph4(t): retires A0(t+1),B0(t+1) (3 newer groups in flight)
// Read-ahead consumes only vmcnt-confirmed regions (audited per phase below).
// Write-after-read: every stage lands >=2 barriers after the last reader's
// compiler-enforced lgkm completion point (audited in R2 notes).
// ============================================================================

__device__ __forceinline__ void bar() {
  asm volatile("" ::: "memory");
  __builtin_amdgcn_s_barrier();
  asm volatile("" ::: "memory");
}

// One half-tile = 256 rows x 32 k of A or B: 2 x global_load_lds(16B)/thread.
#define STAGE(D, R, G, KOFF)                                                  \
  do {                                                                        \
    lds_u32* dst_ = (lds_u32*)(&lds[0]) + (D) * 16384 + (R) * 4096 + t * 4;   \
    const unsigned short* s_ = (G) + (KOFF);                                  \
    __builtin_amdgcn_global_load_lds((gbl_u32*)(s_), dst_, 16, 0, 0);         \
    __builtin_amdgcn_global_load_lds((gbl_u32*)(s_ + (size_t)128 * 2048),     \
                                     dst_ + 2048, 16, 0, 0);                  \
  } while (0)

#define MFMA_PAIR(AF, B0_, B1_, J0, J1)                                       \
  do {                                                                        \
    __builtin_amdgcn_s_setprio(1);                                            \
    _Pragma("unroll")                                                         \
    for (int i = 0; i < 8; ++i) {                                             \
      acc[i][J0] = __builtin_amdgcn_mfma_f32_16x16x32_bf16(AF[i], B0_, acc[i][J0], 0, 0, 0); \
      acc[i][J1] = __builtin_amdgcn_mfma_f32_16x16x32_bf16(AF[i], B1_, acc[i][J1], 0, 0, 0); \
    }                                                                         \
    __builtin_amdgcn_s_setprio(0);                                            \
  } while (0)

// One K-tile (BK=64), buffer D_, tile index T_. Entering invariant:
//   afrA = A-ks0(T_) frags, bA0/bA1 = B-ks0(T_) j0/j1  (read in ph4(T_-1)).
#define KTILE(D_, T_)                                                         \
  do {                                                                        \
    const int c1 = ((T_) + 1 < NT) ? (T_) + 1 : (NT - 1);                     \
    const int c2 = ((T_) + 2 < NT) ? (T_) + 2 : (NT - 1);                     \
    const int k1 = c1 * 64, k2 = c2 * 64;                                     \
    const unsigned short* lA1_  = &lds[(D_) * 32768 + 8192 + aoff];           \
    const unsigned short* lB0_  = &lds[(D_) * 32768 + 16384 + boff];          \
    const unsigned short* lB1_  = &lds[(D_) * 32768 + 24576 + boff];          \
    const unsigned short* lA0n_ = &lds[((D_) ^ 1) * 32768 + aoff];            \
    const unsigned short* lB0n_ = &lds[((D_) ^ 1) * 32768 + 16384 + boff];    \
    /* ph1: read-ahead {bA2,bA3}; stage B1(t+1); MFMA ks0 j01 */              \
    bA2 = *(const bf16x8*)(lB0_ + 1024);                                      \
    bA3 = *(const bf16x8*)(lB0_ + 1536);                                      \
    STAGE((D_) ^ 1, 3, gB, k1 + 32);                                          \
    bar();                                                                    \
    MFMA_PAIR(afrA, bA0, bA1, 0, 1);                                          \
    bar();                                                                    \
    /* ph2: vmcnt confirms B1(t),A1(t); read-ahead {afrB, bB0,bB1} (r1,r3); */\
    /* stage A1(t+1); MFMA ks0 j23 */                                         \
    asm volatile("s_waitcnt vmcnt(6)" ::: "memory");                          \
    _Pragma("unroll")                                                         \
    for (int i = 0; i < 8; ++i) afrB[i] = *(const bf16x8*)(lA1_ + i * 512);   \
    bB0 = *(const bf16x8*)(lB1_);                                             \
    bB1 = *(const bf16x8*)(lB1_ + 512);                                       \
    STAGE((D_) ^ 1, 1, gA, k1 + 32);                                          \
    bar();                                                                    \
    MFMA_PAIR(afrA, bA2, bA3, 2, 3);                                          \
    bar();                                                                    \
    /* ph3: read-ahead {bB2,bB3}; stage A0(t+2); MFMA ks1 j01 */              \
    bB2 = *(const bf16x8*)(lB1_ + 1024);                                      \
    bB3 = *(const bf16x8*)(lB1_ + 1536);                                      \
    STAGE((D_), 0, gA, k2);                                                   \
    bar();                                                                    \
    MFMA_PAIR(afrB, bB0, bB1, 0, 1);                                          \
    bar();                                                                    \
    /* ph4: vmcnt confirms A0(t+1),B0(t+1); read-ahead next tile's            \
       {afrA, bA0,bA1} from D^1 r0/r2; stage B0(t+2); MFMA ks1 j23 */         \
    asm volatile("s_waitcnt vmcnt(6)" ::: "memory");                          \
    _Pragma("unroll")                                                         \
    for (int i = 0; i < 8; ++i) afrA[i] = *(const bf16x8*)(lA0n_ + i * 512);  \
    bA0 = *(const bf16x8*)(lB0n_);                                            \
    bA1 = *(const bf16x8*)(lB0n_ + 512);                                      \
    STAGE((D_), 2, gB, k2);                                                   \
    bar();                                                                    \
    MFMA_PAIR(afrB, bB2, bB3, 2, 3);                                          \
    bar();                                                                    \
  } while (0)

__global__ __launch_bounds__(512, 2) void gemm_bt_256(
    const unsigned short* __restrict__ A,   // [8192][2048] bf16 bits (x)
    const unsigned short* __restrict__ B,   // [8192][2048] bf16 bits (W)
    float* __restrict__ C) {                // [8192][8192] fp32
  constexpr int K = 2048, N = 8192, NT = 32;
  __shared__ unsigned short lds[65536];     // 128 KiB: 2 bufs x 4 x 16 KiB

  const int t = threadIdx.x;
  const int l = t & 63;
  const int w = t >> 6;
  const int wm = w >> 2, wn = w & 3;        // 2M x 4N waves

  // T1: XCD-aware swizzle (1024 wgs, 1024%8==0 -> bijective)
  const int bid = blockIdx.x;
  const int swz = (bid & 7) * 128 + (bid >> 3);
  const int bm = swz >> 5, bn = swz & 31;

  f32x4 acc[8][4] = {};

  // Staging source: thread t covers row (t>>2), 16B chunk (t&3);
  // source chunk pre-swizzled: lchunk = (t&3) ^ ((row>>1)&3), row bits 1-2 =
  // t bits 3-4 (row+128 preserves them).
  const int lchunk = (t & 3) ^ ((t >> 3) & 3);
  const unsigned short* gA = A + (size_t)(bm * 256 + (t >> 2)) * K + lchunk * 8;
  const unsigned short* gB = B + (size_t)(bn * 256 + (t >> 2)) * K + lchunk * 8;

  // Frag-read offsets: row*32 + swizzled 16B-chunk*8 (R2-verified, 0 conflicts).
  const int sc8 = ((l >> 4) ^ ((l >> 1) & 3)) * 8;
  const int aoff = (wm * 128 + (l & 15)) * 32 + sc8;
  const int boff = (wn * 64 + (l & 15)) * 32 + sc8;

  bf16x8 afrA[8], afrB[8], bA0, bA1, bA2, bA3, bB0, bB1, bB2, bB3;

  // Prologue (ledger g1..g6): stage tile0 fully + tile1's A0/B0, retire g1,g2
  // (tile0 A0/B0) via vmcnt(8), then pre-read ph1(0)'s operands.
  STAGE(0, 0, gA, 0);    // g1 A0(0)
  STAGE(0, 2, gB, 0);    // g2 B0(0)
  STAGE(0, 3, gB, 32);   // g3 B1(0)
  STAGE(0, 1, gA, 32);   // g4 A1(0)
  STAGE(1, 0, gA, 64);   // g5 A0(1)
  STAGE(1, 2, gB, 64);   // g6 B0(1)
  asm volatile("s_waitcnt vmcnt(8)" ::: "memory");
  bar();
#pragma unroll
  for (int i = 0; i < 8; ++i) afrA[i] = *(const bf16x8*)(&lds[aoff] + i * 512);
  bA0 = *(const bf16x8*)(&lds[16384 + boff]);
  bA1 = *(const bf16x8*)(&lds[16384 + boff] + 512);

  for (int T = 0; T < NT; T += 2) {   // 2 K-tiles / iter -> static buffer idx
    KTILE(0, T);
    KTILE(1, T + 1);
  }
  asm volatile("s_waitcnt vmcnt(0)" ::: "memory");  // drain tail dummies

  // Epilogue: C/D layout col=lane&15, row=(lane>>4)*4+reg (m89/m91-verified)
  float* Cp = C + (size_t)(bm * 256 + wm * 128 + ((l >> 4) << 2)) * N
              + bn * 256 + wn * 64 + (l & 15);
#pragma unroll
  for (int i = 0; i < 8; ++i)
#pragma unroll
    for (int j = 0; j < 4; ++j)
#pragma unroll
      for (int r = 0; r < 4; ++r)
        Cp[(size_t)(i * 16 + r) * N + j * 16] = acc[i][j][r];
}

extern "C" void kernel_launch(void* const* d_in, const int* in_sizes, int n_in,
                              void* d_out, int out_size, void* d_ws, size_t ws_size,
                              hipStream_t stream) {
  const float* x     = (const float*)d_in[0];   // [4,2048,2048] fp32
  const int*   gi    = (const int*)d_in[1];     // [8192,2048] int32
  const float* scale = (const float*)d_in[2];   // scalar
  const float* lut   = (const float*)d_in[3];   // [15] fp32
  float* out = (float*)d_out;                   // [4,2048,8192] fp32

  const int M = 8192, N = 8192, K = 2048;
  unsigned short* xb = (unsigned short*)d_ws;          // 32 MiB bf16 x
  unsigned short* wb = xb + (size_t)M * K;             // 32 MiB bf16 W

  long nx = (long)M * K;
  long nw = (long)N * K;
  cvt_x_kernel<<<dim3((unsigned)(nx / (256 * 8))), dim3(256), 0, stream>>>(x, xb, nx);
  dequant_kernel<<<dim3((unsigned)(nw / (256 * 8))), dim3(256), 0, stream>>>(gi, lut, scale, wb, nw);

  gemm_bt_256<<<dim3((M / 256) * (N / 256)), dim3(512), 0, stream>>>(xb, wb, out);
}

// Round 4
// 567.974 us; speedup vs baseline: 1.0727x; 1.0727x over previous
//
#include <hip/hip_runtime.h>
#include <cstdint>

// ---- types ----
typedef short bf16x8 __attribute__((ext_vector_type(8)));        // 8 bf16 in 4 VGPRs
typedef unsigned short u16x8 __attribute__((ext_vector_type(8)));
typedef float f32x4 __attribute__((ext_vector_type(4)));
typedef __attribute__((address_space(3))) uint32_t lds_u32;
typedef const __attribute__((address_space(1))) uint32_t gbl_u32;

// fp32 -> bf16 bits, round-to-nearest-even
__device__ __forceinline__ unsigned short f2bf(float f) {
  union { float f; uint32_t u; } c; c.f = f;
  uint32_t u = c.u;
  return (unsigned short)((u + 0x7fffu + ((u >> 16) & 1u)) >> 16);
}

// ---- x fp32 -> bf16, 8 elems/thread ----
__global__ void cvt_x_kernel(const float* __restrict__ x,
                             unsigned short* __restrict__ y, long n) {
  long t = (long)blockIdx.x * blockDim.x + threadIdx.x;
  long base = t * 8;
  if (base >= n) return;
  const float4* p = (const float4*)(x + base);
  float4 f0 = p[0], f1 = p[1];
  u16x8 v;
  v[0] = f2bf(f0.x); v[1] = f2bf(f0.y); v[2] = f2bf(f0.z); v[3] = f2bf(f0.w);
  v[4] = f2bf(f1.x); v[5] = f2bf(f1.y); v[6] = f2bf(f1.z); v[7] = f2bf(f1.w);
  *(u16x8*)(y + base) = v;
}

// ---- W dequant: bf16(lut[idx] * scale), 8 elems/thread ----
__global__ void dequant_kernel(const int* __restrict__ idx,
                               const float* __restrict__ lut,
                               const float* __restrict__ scale,
                               unsigned short* __restrict__ w, long n) {
  __shared__ unsigned short slut[16];
  if (threadIdx.x < 15) slut[threadIdx.x] = f2bf(lut[threadIdx.x] * scale[0]);
  __syncthreads();
  long t = (long)blockIdx.x * blockDim.x + threadIdx.x;
  long base = t * 8;
  if (base >= n) return;
  const int4* p = (const int4*)(idx + base);
  int4 i0 = p[0], i1 = p[1];
  u16x8 v;
  v[0] = slut[i0.x]; v[1] = slut[i0.y]; v[2] = slut[i0.z]; v[3] = slut[i0.w];
  v[4] = slut[i1.x]; v[5] = slut[i1.y]; v[6] = slut[i1.z]; v[7] = slut[i1.w];
  *(u16x8*)(w + base) = v;
}

// ============================================================================
// bf16 NT-GEMM, 256x256 tile, BK=64, 8 waves (2Mx4N), 8-phase schedule with
// read-ahead (R3) + SUPER-TILE XCD swizzle (R4).
//
// R4 change (only): block->tile mapping. R3's row-band mapping put 1bm x 32bn
// resident per XCD -> 33 MiB B working set per 4 MiB L2, 8x HBM re-fetch
// (FETCH 528 MiB vs 64 MiB unique), vmcnt-supply stall ~740 cyc/phase.
// New mapping: 32 supertiles of 4bm x 8bn (32 blocks each); XCD x (= bid&7)
// walks supertiles (sm=x, sn=round). Resident per XCD: A 4 MiB (each panel
// shared by 8 blocks) + B 8 MiB (each shared by 4) -> L2-dominated staging;
// all XCDs share the same 8 B panels via L3 (active unique set 40 MiB).
//
// LDS per buffer (32K elems): r0=A ks0 [256][32], r1=A ks1, r2=B ks0, r3=B ks1.
// T2 swizzle (R2-verified, 0 conflicts): stored_chunk = chunk ^ ((row>>1)&3),
// applied on the global SOURCE of global_load_lds + the ds_read address.
//
// Stage ledger (group g = one STAGE = 2 loads), tile t, D = t&1:
//   g(4t+3): ph1(t) B1(t+1)->D^1 r3     g(4t+4): ph2(t) A1(t+1)->D^1 r1
//   g(4t+5): ph3(t) A0(t+2)->D  r0     g(4t+6): ph4(t) B0(t+2)->D  r2
// vmcnt(6) @ph2(t): retires B1(t),A1(t); @ph4(t): retires A0(t+1),B0(t+1).
// ============================================================================

__device__ __forceinline__ void bar() {
  asm volatile("" ::: "memory");
  __builtin_amdgcn_s_barrier();
  asm volatile("" ::: "memory");
}

// One half-tile = 256 rows x 32 k of A or B: 2 x global_load_lds(16B)/thread.
#define STAGE(D, R, G, KOFF)                                                  \
  do {                                                                        \
    lds_u32* dst_ = (lds_u32*)(&lds[0]) + (D) * 16384 + (R) * 4096 + t * 4;   \
    const unsigned short* s_ = (G) + (KOFF);                                  \
    __builtin_amdgcn_global_load_lds((gbl_u32*)(s_), dst_, 16, 0, 0);         \
    __builtin_amdgcn_global_load_lds((gbl_u32*)(s_ + (size_t)128 * 2048),     \
                                     dst_ + 2048, 16, 0, 0);                  \
  } while (0)

#define MFMA_PAIR(AF, B0_, B1_, J0, J1)                                       \
  do {                                                                        \
    __builtin_amdgcn_s_setprio(1);                                            \
    _Pragma("unroll")                                                         \
    for (int i = 0; i < 8; ++i) {                                             \
      acc[i][J0] = __builtin_amdgcn_mfma_f32_16x16x32_bf16(AF[i], B0_, acc[i][J0], 0, 0, 0); \
      acc[i][J1] = __builtin_amdgcn_mfma_f32_16x16x32_bf16(AF[i], B1_, acc[i][J1], 0, 0, 0); \
    }                                                                         \
    __builtin_amdgcn_s_setprio(0);                                            \
  } while (0)

// One K-tile (BK=64), buffer D_, tile index T_. Entering invariant:
//   afrA = A-ks0(T_) frags, bA0/bA1 = B-ks0(T_) j0/j1  (read in ph4(T_-1)).
#define KTILE(D_, T_)                                                         \
  do {                                                                        \
    const int c1 = ((T_) + 1 < NT) ? (T_) + 1 : (NT - 1);                     \
    const int c2 = ((T_) + 2 < NT) ? (T_) + 2 : (NT - 1);                     \
    const int k1 = c1 * 64, k2 = c2 * 64;                                     \
    const unsigned short* lA1_  = &lds[(D_) * 32768 + 8192 + aoff];           \
    const unsigned short* lB0_  = &lds[(D_) * 32768 + 16384 + boff];          \
    const unsigned short* lB1_  = &lds[(D_) * 32768 + 24576 + boff];          \
    const unsigned short* lA0n_ = &lds[((D_) ^ 1) * 32768 + aoff];            \
    const unsigned short* lB0n_ = &lds[((D_) ^ 1) * 32768 + 16384 + boff];    \
    /* ph1: read-ahead {bA2,bA3}; stage B1(t+1); MFMA ks0 j01 */              \
    bA2 = *(const bf16x8*)(lB0_ + 1024);                                      \
    bA3 = *(const bf16x8*)(lB0_ + 1536);                                      \
    STAGE((D_) ^ 1, 3, gB, k1 + 32);                                          \
    bar();                                                                    \
    MFMA_PAIR(afrA, bA0, bA1, 0, 1);                                          \
    bar();                                                                    \
    /* ph2: vmcnt confirms B1(t),A1(t); read-ahead {afrB, bB0,bB1} (r1,r3); */\
    /* stage A1(t+1); MFMA ks0 j23 */                                         \
    asm volatile("s_waitcnt vmcnt(6)" ::: "memory");                          \
    _Pragma("unroll")                                                         \
    for (int i = 0; i < 8; ++i) afrB[i] = *(const bf16x8*)(lA1_ + i * 512);   \
    bB0 = *(const bf16x8*)(lB1_);                                             \
    bB1 = *(const bf16x8*)(lB1_ + 512);                                       \
    STAGE((D_) ^ 1, 1, gA, k1 + 32);                                          \
    bar();                                                                    \
    MFMA_PAIR(afrA, bA2, bA3, 2, 3);                                          \
    bar();                                                                    \
    /* ph3: read-ahead {bB2,bB3}; stage A0(t+2); MFMA ks1 j01 */              \
    bB2 = *(const bf16x8*)(lB1_ + 1024);                                      \
    bB3 = *(const bf16x8*)(lB1_ + 1536);                                      \
    STAGE((D_), 0, gA, k2);                                                   \
    bar();                                                                    \
    MFMA_PAIR(afrB, bB0, bB1, 0, 1);                                          \
    bar();                                                                    \
    /* ph4: vmcnt confirms A0(t+1),B0(t+1); read-ahead next tile's            \
       {afrA, bA0,bA1} from D^1 r0/r2; stage B0(t+2); MFMA ks1 j23 */         \
    asm volatile("s_waitcnt vmcnt(6)" ::: "memory");                          \
    _Pragma("unroll")                                                         \
    for (int i = 0; i < 8; ++i) afrA[i] = *(const bf16x8*)(lA0n_ + i * 512);  \
    bA0 = *(const bf16x8*)(lB0n_);                                            \
    bA1 = *(const bf16x8*)(lB0n_ + 512);                                      \
    STAGE((D_), 2, gB, k2);                                                   \
    bar();                                                                    \
    MFMA_PAIR(afrB, bB2, bB3, 2, 3);                                          \
    bar();                                                                    \
  } while (0)

__global__ __launch_bounds__(512, 2) void gemm_bt_256(
    const unsigned short* __restrict__ A,   // [8192][2048] bf16 bits (x)
    const unsigned short* __restrict__ B,   // [8192][2048] bf16 bits (W)
    float* __restrict__ C) {                // [8192][8192] fp32
  constexpr int K = 2048, N = 8192, NT = 32;
  __shared__ unsigned short lds[65536];     // 128 KiB: 2 bufs x 4 x 16 KiB

  const int t = threadIdx.x;
  const int l = t & 63;
  const int w = t >> 6;
  const int wm = w >> 2, wn = w & 3;        // 2M x 4N waves

  // R4 super-tile XCD swizzle: 32 supertiles of 4bm x 8bn, 32 blocks each.
  // XCD x = bid&7 handles supertile (sm=x, sn=round). Bijective: (x, sn, j)
  // <-> (bm, bn). Resident per XCD = 4bm x 8bn -> L2-shared A(8x)/B(4x).
  const int bid = blockIdx.x;
  const int x_ = bid & 7;            // XCD (round-robin dispatch premise)
  const int i_ = bid >> 3;           // per-XCD sequence 0..127
  const int sn = i_ >> 5;            // supertile column round 0..3
  const int j_ = i_ & 31;            // block within supertile
  const int bm = x_ * 4 + (j_ >> 3);
  const int bn = sn * 8 + (j_ & 7);

  f32x4 acc[8][4] = {};

  // Staging source: thread t covers row (t>>2), 16B chunk (t&3);
  // source chunk pre-swizzled: lchunk = (t&3) ^ ((row>>1)&3), row bits 1-2 =
  // t bits 3-4 (row+128 preserves them).
  const int lchunk = (t & 3) ^ ((t >> 3) & 3);
  const unsigned short* gA = A + (size_t)(bm * 256 + (t >> 2)) * K + lchunk * 8;
  const unsigned short* gB = B + (size_t)(bn * 256 + (t >> 2)) * K + lchunk * 8;

  // Frag-read offsets: row*32 + swizzled 16B-chunk*8 (R2-verified, 0 conflicts).
  const int sc8 = ((l >> 4) ^ ((l >> 1) & 3)) * 8;
  const int aoff = (wm * 128 + (l & 15)) * 32 + sc8;
  const int boff = (wn * 64 + (l & 15)) * 32 + sc8;

  bf16x8 afrA[8], afrB[8], bA0, bA1, bA2, bA3, bB0, bB1, bB2, bB3;

  // Prologue (ledger g1..g6): stage tile0 fully + tile1's A0/B0, retire g1,g2
  // (tile0 A0/B0) via vmcnt(8), then pre-read ph1(0)'s operands.
  STAGE(0, 0, gA, 0);    // g1 A0(0)
  STAGE(0, 2, gB, 0);    // g2 B0(0)
  STAGE(0, 3, gB, 32);   // g3 B1(0)
  STAGE(0, 1, gA, 32);   // g4 A1(0)
  STAGE(1, 0, gA, 64);   // g5 A0(1)
  STAGE(1, 2, gB, 64);   // g6 B0(1)
  asm volatile("s_waitcnt vmcnt(8)" ::: "memory");
  bar();
#pragma unroll
  for (int i = 0; i < 8; ++i) afrA[i] = *(const bf16x8*)(&lds[aoff] + i * 512);
  bA0 = *(const bf16x8*)(&lds[16384 + boff]);
  bA1 = *(const bf16x8*)(&lds[16384 + boff] + 512);

  for (int T = 0; T < NT; T += 2) {   // 2 K-tiles / iter -> static buffer idx
    KTILE(0, T);
    KTILE(1, T + 1);
  }
  asm volatile("s_waitcnt vmcnt(0)" ::: "memory");  // drain tail dummies

  // Epilogue: C/D layout col=lane&15, row=(lane>>4)*4+reg (m89/m91-verified)
  float* Cp = C + (size_t)(bm * 256 + wm * 128 + ((l >> 4) << 2)) * N
              + bn * 256 + wn * 64 + (l & 15);
#pragma unroll
  for (int i = 0; i < 8; ++i)
#pragma unroll
    for (int j = 0; j < 4; ++j)
#pragma unroll
      for (int r = 0; r < 4; ++r)
        Cp[(size_t)(i * 16 + r) * N + j * 16] = acc[i][j][r];
}

extern "C" void kernel_launch(void* const* d_in, const int* in_sizes, int n_in,
                              void* d_out, int out_size, void* d_ws, size_t ws_size,
                              hipStream_t stream) {
  const float* x     = (const float*)d_in[0];   // [4,2048,2048] fp32
  const int*   gi    = (const int*)d_in[1];     // [8192,2048] int32
  const float* scale = (const float*)d_in[2];   // scalar
  const float* lut   = (const float*)d_in[3];   // [15] fp32
  float* out = (float*)d_out;                   // [4,2048,8192] fp32

  const int M = 8192, N = 8192, K = 2048;
  unsigned short* xb = (unsigned short*)d_ws;          // 32 MiB bf16 x
  unsigned short* wb = xb + (size_t)M * K;             // 32 MiB bf16 W

  long nx = (long)M * K;
  long nw = (long)N * K;
  cvt_x_kernel<<<dim3((unsigned)(nx / (256 * 8))), dim3(256), 0, stream>>>(x, xb, nx);
  dequant_kernel<<<dim3((unsigned)(nw / (256 * 8))), dim3(256), 0, stream>>>(gi, lut, scale, wb, nw);

  gemm_bt_256<<<dim3((M / 256) * (N / 256)), dim3(512), 0, stream>>>(xb, wb, out);
}